// Round 8
// baseline (229.329 us; speedup 1.0000x reference)
//
#include <hip/hip_runtime.h>

#define BATCH   4096
#define IN_F    1024
#define OUT_F   1024
#define KF      8
#define KD      14336          /* trimmed GEMM K-dim: (7 sin + 7 cos) * 1024, feature-major */

#define BM 256
#define BN 256
#define BK 64
#define KSPLIT 4
#define KCHUNK (KD/KSPLIT)     /* 3584 */
#define NT (KCHUNK/BK)         /* 56 K-tiles per block */
#define C_ELEMS ((size_t)BATCH * OUT_F)

typedef short short8 __attribute__((ext_vector_type(8)));
typedef float f32x4  __attribute__((ext_vector_type(4)));

// bf16 round-to-nearest-even from f32 (bit pattern in ushort)
__device__ __forceinline__ unsigned short f2bf(float f) {
  union { float f; unsigned int u; } v; v.f = f;
  unsigned int u = v.u;
  unsigned int lsb = (u >> 16) & 1u;
  u += 0x7fffu + lsb;
  return (unsigned short)(u >> 16);
}

__device__ __forceinline__ unsigned int pack2(float lo, float hi) {
  return (unsigned int)f2bf(lo) | ((unsigned int)f2bf(hi) << 16);
}

__device__ __forceinline__ void gload_lds16(const void* g, void* l) {
  __builtin_amdgcn_global_load_lds((const __attribute__((address_space(1))) void*)g,
                                   (__attribute__((address_space(3))) void*)l,
                                   16, 0, 0);
}

// ---------------- W conversion (k=0 trimmed, feature-major, i-pair) + bias ----------------
// Thread per (o, i-pair): 14 coalesced 4B stores; 128B/lane contiguous loads.
__global__ __launch_bounds__(256) void wconv_kernel(const float* __restrict__ a,
                                                    const float* __restrict__ b,
                                                    unsigned short* __restrict__ W,
                                                    float* __restrict__ bias) {
  int idx = blockIdx.x * 256 + threadIdx.x;
  int o  = idx >> 9;
  int i0 = (idx & 511) * 2;
  const float4* ap = reinterpret_cast<const float4*>(a + (size_t)o * 8192 + i0 * 8);
  const float4* bp = reinterpret_cast<const float4*>(b + (size_t)o * 8192 + i0 * 8);
  float4 a0 = ap[0], a1 = ap[1], a2 = ap[2], a3 = ap[3];   // i0: k0-3, k4-7; i0+1: k0-3, k4-7
  float4 b0 = bp[0], b1 = bp[1], b2 = bp[2], b3 = bp[3];

  unsigned int* wp = reinterpret_cast<unsigned int*>(W + (size_t)o * KD + i0);
  wp[ 0 * IN_F / 2] = pack2(a0.y, a2.y);
  wp[ 1 * IN_F / 2] = pack2(a0.z, a2.z);
  wp[ 2 * IN_F / 2] = pack2(a0.w, a2.w);
  wp[ 3 * IN_F / 2] = pack2(a1.x, a3.x);
  wp[ 4 * IN_F / 2] = pack2(a1.y, a3.y);
  wp[ 5 * IN_F / 2] = pack2(a1.z, a3.z);
  wp[ 6 * IN_F / 2] = pack2(a1.w, a3.w);
  wp[ 7 * IN_F / 2] = pack2(b0.y, b2.y);
  wp[ 8 * IN_F / 2] = pack2(b0.z, b2.z);
  wp[ 9 * IN_F / 2] = pack2(b0.w, b2.w);
  wp[10 * IN_F / 2] = pack2(b1.x, b3.x);
  wp[11 * IN_F / 2] = pack2(b1.y, b3.y);
  wp[12 * IN_F / 2] = pack2(b1.z, b3.z);
  wp[13 * IN_F / 2] = pack2(b1.w, b3.w);

  // bias[o] = sum_i b[o,i,0]; one o per block (2 blocks per o), exact f32
  float bsum = b0.x + b2.x;
#pragma unroll
  for (int off = 32; off > 0; off >>= 1) bsum += __shfl_down(bsum, off);
  __shared__ float red[4];
  if ((threadIdx.x & 63) == 0) red[threadIdx.x >> 6] = bsum;
  __syncthreads();
  if (threadIdx.x == 0) atomicAdd(&bias[o], red[0] + red[1] + red[2] + red[3]);
}

// ---------------- feature kernel (feature-major, i-pair): Xf[b][j*1024+i] ----------------
__global__ __launch_bounds__(256) void feat_kernel(const float* __restrict__ x,
                                                   unsigned short* __restrict__ Xf) {
  int idx = blockIdx.x * 256 + threadIdx.x;
  int bb = idx >> 9;
  int i0 = (idx & 511) * 2;
  float2 xv = *reinterpret_cast<const float2*>(x + (size_t)bb * IN_F + i0);
  float s1a, c1a, s1b, c1b;
  sincosf(xv.x, &s1a, &c1a);
  sincosf(xv.y, &s1b, &c1b);
  float sa[KF], ca[KF], sb_[KF], cb[KF];
  sa[1] = s1a; ca[1] = c1a; sb_[1] = s1b; cb[1] = c1b;
#pragma unroll
  for (int k = 2; k < KF; ++k) {
    sa[k]  = sa[k-1]*c1a + ca[k-1]*s1a;
    ca[k]  = ca[k-1]*c1a - sa[k-1]*s1a;
    sb_[k] = sb_[k-1]*c1b + cb[k-1]*s1b;
    cb[k]  = cb[k-1]*c1b - sb_[k-1]*s1b;
  }
  unsigned int* dst = reinterpret_cast<unsigned int*>(Xf + (size_t)bb * KD + i0);
#pragma unroll
  for (int j = 0; j < 7; ++j) dst[j * IN_F / 2]       = pack2(sa[j + 1], sb_[j + 1]);
#pragma unroll
  for (int j = 0; j < 7; ++j) dst[(7 + j) * IN_F / 2] = pack2(ca[j + 1], cb[j + 1]);
}

// ---------------- GEMM: 256x256 tile, 4 waves x (128x128), 1 wave/SIMD ----------------
// acc[8][8] f32x4 (~256 VGPR; 512-reg budget via launch_bounds(256,1)). LDS reads per
// tile per CU drop 192 -> 128 b128 (each wave reads A 128 rows + B 128 rows; no 4-way
// panel re-read) -> LDS-port 2306 cy <= MFMA 2483 cy: matrix pipe becomes the binding
// resource. Overlap via within-wave ILP: ds_read issue precedes its MFMA group by a
// full 8-MFMA pipe shadow; bf(ks1) burst placed inside ks0's MFMA stream. One counted
// stage burst (16 gloads, ~2400 cy lead) + single vmcnt(0)+barrier per tile.
// T2 XOR swizzle via pre-swizzled global source + swizzled ds_read (0 conflicts R2-R7).
__global__ __launch_bounds__(256, 1) void gemm_kernel(const unsigned short* __restrict__ A,
                                                      const unsigned short* __restrict__ Bt,
                                                      float* __restrict__ Cout,
                                                      int use_slab) {
  __shared__ unsigned short sA[2][BM * BK];   // 32 KiB each
  __shared__ unsigned short sB[2][BN * BK];

  const int tid  = threadIdx.x;
  const int wid  = tid >> 6;
  const int lane = tid & 63;
  const int wm = wid >> 1, wn = wid & 1;      // 2x2 wave grid, 128x128 each

  // bijective XCD swizzle: 256 blocks % 8 XCDs == 0; 32 consecutive work items/XCD
  const int bid = blockIdx.x;
  const int s   = (bid & 7) * 32 + (bid >> 3);
  const int z   = s >> 6;          // K-split chunk 0..3
  const int mt  = s & 15;          // m-tile fastest -> XCD shares W panels in L2
  const int nt  = (s >> 4) & 3;
  const int m0  = mt * BM;
  const int n0  = nt * BN;
  const int fbase = z * KCHUNK;

  // ---- staging addressing: 2 slots per wave (rows wid*8.. and (wid+4)*8..) ----
  const int gsw = (lane & 7) ^ (lane >> 3);   // swizzled 16B granule (involution)
  const unsigned short* pA0 = A  + (size_t)(m0 + wid * 8       + (lane >> 3)) * KD + fbase + gsw * 8;
  const unsigned short* pA1 = A  + (size_t)(m0 + (wid + 4) * 8 + (lane >> 3)) * KD + fbase + gsw * 8;
  const unsigned short* pB0 = Bt + (size_t)(n0 + wid * 8       + (lane >> 3)) * KD + fbase + gsw * 8;
  const unsigned short* pB1 = Bt + (size_t)(n0 + (wid + 4) * 8 + (lane >> 3)) * KD + fbase + gsw * 8;
  const int ld0 = wid * 512;
  const int ld1 = (wid + 4) * 512;

  // ---- fragment read addressing (swizzled) ----
  const int l15 = lane & 15;
  int kfrag[2];
#pragma unroll
  for (int ks = 0; ks < 2; ++ks)
    kfrag[ks] = ((ks * 64 + (lane >> 4) * 16) ^ ((lane & 7) << 4)) >> 1;
  const int arow = wm * 128 + l15;
  const int brow = wn * 128 + l15;

  f32x4 acc[8][8] = {};

#define STAGE(BUF, KOFF)                                                        \
  {                                                                             \
    _Pragma("unroll") for (int g = 0; g < 4; ++g) {                             \
      gload_lds16(pA0 + (size_t)g * 64 * KD + (KOFF), &sA[BUF][g * 4096 + ld0]);\
      gload_lds16(pA1 + (size_t)g * 64 * KD + (KOFF), &sA[BUF][g * 4096 + ld1]);\
      gload_lds16(pB0 + (size_t)g * 64 * KD + (KOFF), &sB[BUF][g * 4096 + ld0]);\
      gload_lds16(pB1 + (size_t)g * 64 * KD + (KOFF), &sB[BUF][g * 4096 + ld1]);\
    }                                                                           \
  }

  // ---- prologue: stage tile 0 -> buf 0 ----
  STAGE(0, 0)
  asm volatile("s_waitcnt vmcnt(0)\n\ts_barrier" ::: "memory");

  for (int t = 0; t < NT; ++t) {
    const int c  = t & 1;
    const int cn = c ^ 1;
    const int ktn = (t + 1 < NT) ? (t + 1) * BK : 0;   // dead-wrap keeps ledger uniform
    const unsigned short* sAc = &sA[c][0];
    const unsigned short* sBc = &sB[c][0];

    // stage next tile into the other buffer (WAR safe: published by previous barrier)
    if (cn) STAGE(1, ktn) else STAGE(0, ktn)

    // ks = 0, mf 0..3 (bf0 read burst first)
    short8 bf0[8], bf1[8];
#pragma unroll
    for (int nf = 0; nf < 8; ++nf)
      bf0[nf] = *reinterpret_cast<const short8*>(sBc + (brow + nf * 16) * 64 + kfrag[0]);
#pragma unroll
    for (int mf = 0; mf < 4; ++mf) {
      short8 af = *reinterpret_cast<const short8*>(sAc + (arow + mf * 16) * 64 + kfrag[0]);
#pragma unroll
      for (int nf = 0; nf < 8; ++nf)
        acc[mf][nf] = __builtin_amdgcn_mfma_f32_16x16x32_bf16(af, bf0[nf], acc[mf][nf], 0, 0, 0);
    }
    // bf(ks1) burst hidden under ks0's remaining MFMA stream
#pragma unroll
    for (int nf = 0; nf < 8; ++nf)
      bf1[nf] = *reinterpret_cast<const short8*>(sBc + (brow + nf * 16) * 64 + kfrag[1]);
#pragma unroll
    for (int mf = 4; mf < 8; ++mf) {
      short8 af = *reinterpret_cast<const short8*>(sAc + (arow + mf * 16) * 64 + kfrag[0]);
#pragma unroll
      for (int nf = 0; nf < 8; ++nf)
        acc[mf][nf] = __builtin_amdgcn_mfma_f32_16x16x32_bf16(af, bf0[nf], acc[mf][nf], 0, 0, 0);
    }
    // ks = 1
#pragma unroll
    for (int mf = 0; mf < 8; ++mf) {
      short8 af = *reinterpret_cast<const short8*>(sAc + (arow + mf * 16) * 64 + kfrag[1]);
#pragma unroll
      for (int nf = 0; nf < 8; ++nf)
        acc[mf][nf] = __builtin_amdgcn_mfma_f32_16x16x32_bf16(af, bf1[nf], acc[mf][nf], 0, 0, 0);
    }

    // publish staged buffer; staged loads had a full tile (~2400 cy) to land
    asm volatile("s_waitcnt vmcnt(0)\n\ts_barrier" ::: "memory");
  }
#undef STAGE

  // ---- epilogue ----
  const int crow = m0 + wm * 128 + (lane >> 4) * 4;
  const int ccol = n0 + wn * 128 + l15;
  if (use_slab) {
    float* Cz = Cout + (size_t)z * C_ELEMS;
#pragma unroll
    for (int mf = 0; mf < 8; ++mf)
#pragma unroll
      for (int nf = 0; nf < 8; ++nf)
#pragma unroll
        for (int j = 0; j < 4; ++j)
          Cz[(size_t)(crow + mf * 16 + j) * OUT_F + ccol + nf * 16] = acc[mf][nf][j];
  } else {
#pragma unroll
    for (int mf = 0; mf < 8; ++mf)
#pragma unroll
      for (int nf = 0; nf < 8; ++nf)
#pragma unroll
        for (int j = 0; j < 4; ++j)
          atomicAdd(&Cout[(size_t)(crow + mf * 16 + j) * OUT_F + ccol + nf * 16],
                    acc[mf][nf][j]);
  }
}

// ---------------- K-split slab reduce + bias: y = s0+s1+s2+s3 + bias[o] ----------------
__global__ __launch_bounds__(256) void reduce_kernel(const f32x4* __restrict__ s,
                                                     const float* __restrict__ bias,
                                                     f32x4* __restrict__ y) {
  size_t i = (size_t)blockIdx.x * 256 + threadIdx.x;
  const size_t NQ = C_ELEMS / 4;
  f32x4 v = s[i] + s[i + NQ] + s[i + 2 * NQ] + s[i + 3 * NQ];
  v += reinterpret_cast<const f32x4*>(bias)[i & 255];   // OUT_F/4 = 256 per row
  y[i] = v;
}

// ---------------- bias broadcast (atomic-fallback init): y[b][o] = bias[o] ----------------
__global__ __launch_bounds__(256) void binit_kernel(const float* __restrict__ bias,
                                                    f32x4* __restrict__ y) {
  size_t i = (size_t)blockIdx.x * 256 + threadIdx.x;
  y[i] = reinterpret_cast<const f32x4*>(bias)[i & 255];
}

// ---------------- fallback (no workspace): direct f32 evaluation ----------------
__global__ __launch_bounds__(256) void naive_kernel(const float* __restrict__ x,
                                                    const float* __restrict__ a,
                                                    const float* __restrict__ b,
                                                    float* __restrict__ y) {
  int o  = blockIdx.x * 256 + threadIdx.x;
  int bb = blockIdx.y;
  __shared__ float xs[IN_F];
  for (int i = threadIdx.x; i < IN_F; i += 256) xs[i] = x[(size_t)bb * IN_F + i];
  __syncthreads();
  float acc = 0.f;
  for (int i = 0; i < IN_F; ++i) {
    float s1, c1; sincosf(xs[i], &s1, &c1);
    float sk = 0.f, ck = 1.f;
    const float* ap = a + (size_t)o * 8192 + i * KF;
    const float* bp = b + (size_t)o * 8192 + i * KF;
#pragma unroll
    for (int k = 0; k < KF; ++k) {
      acc += sk * ap[k] + ck * bp[k];
      float sn = sk * c1 + ck * s1;
      ck = ck * c1 - sk * s1;
      sk = sn;
    }
  }
  y[(size_t)bb * OUT_F + o] = acc;
}

extern "C" void kernel_launch(void* const* d_in, const int* in_sizes, int n_in,
                              void* d_out, int out_size, void* d_ws, size_t ws_size,
                              hipStream_t stream) {
  (void)in_sizes; (void)n_in; (void)out_size;
  const float* x = (const float*)d_in[0];
  const float* a = (const float*)d_in[1];
  const float* b = (const float*)d_in[2];
  float* y = (float*)d_out;

  const size_t XF_BYTES   = (size_t)BATCH * KD * sizeof(unsigned short);   // 112 MiB
  const size_t W_BYTES    = (size_t)OUT_F * KD * sizeof(unsigned short);   // 28 MiB
  const size_t BIAS_BYTES = (size_t)OUT_F * sizeof(float);                 // 4 KiB
  const size_t SLAB_BYTES = C_ELEMS * sizeof(float) * KSPLIT;              // 64 MiB

  if (ws_size >= XF_BYTES + W_BYTES + BIAS_BYTES) {
    unsigned short* Xf = (unsigned short*)d_ws;
    unsigned short* W  = (unsigned short*)((char*)d_ws + XF_BYTES);
    float* bias        = (float*)((char*)d_ws + XF_BYTES + W_BYTES);
    float* slabs       = (float*)((char*)d_ws + XF_BYTES + W_BYTES + BIAS_BYTES);
    const bool slab = ws_size >= XF_BYTES + W_BYTES + BIAS_BYTES + SLAB_BYTES;

    hipMemsetAsync(bias, 0, BIAS_BYTES, stream);
    wconv_kernel<<<(OUT_F * IN_F / 2) / 256, 256, 0, stream>>>(a, b, W, bias);
    feat_kernel<<<(BATCH * IN_F / 2) / 256, 256, 0, stream>>>(x, Xf);
    if (slab) {
      gemm_kernel<<<dim3((BATCH / BM) * (OUT_F / BN) * KSPLIT), 256, 0, stream>>>(Xf, W, slabs, 1);
      reduce_kernel<<<(int)(C_ELEMS / 4 / 256), 256, 0, stream>>>((const f32x4*)slabs, bias, (f32x4*)y);
    } else {
      binit_kernel<<<(int)(C_ELEMS / 4 / 256), 256, 0, stream>>>(bias, (f32x4*)y);
      gemm_kernel<<<dim3((BATCH / BM) * (OUT_F / BN) * KSPLIT), 256, 0, stream>>>(Xf, W, y, 0);
    }
  } else {
    naive_kernel<<<dim3(OUT_F / 256, BATCH), 256, 0, stream>>>(x, a, b, y);
  }
}

// Round 9
// 178.469 us; speedup vs baseline: 1.2850x; 1.2850x over previous
//
#include <hip/hip_runtime.h>

#define BATCH   4096
#define IN_F    1024
#define OUT_F   1024
#define KF      8
#define KD      14336          /* trimmed GEMM K-dim: (7 sin + 7 cos) * 1024, feature-major */

#define BM 256
#define BN 256
#define BK 64
#define KSPLIT 4
#define KCHUNK (KD/KSPLIT)     /* 3584 */
#define NT (KCHUNK/BK)         /* 56 K-tiles per block */
#define C_ELEMS ((size_t)BATCH * OUT_F)

typedef short short8 __attribute__((ext_vector_type(8)));
typedef float f32x4  __attribute__((ext_vector_type(4)));

// bf16 round-to-nearest-even from f32 (bit pattern in ushort)
__device__ __forceinline__ unsigned short f2bf(float f) {
  union { float f; unsigned int u; } v; v.f = f;
  unsigned int u = v.u;
  unsigned int lsb = (u >> 16) & 1u;
  u += 0x7fffu + lsb;
  return (unsigned short)(u >> 16);
}

__device__ __forceinline__ unsigned int pack2(float lo, float hi) {
  return (unsigned int)f2bf(lo) | ((unsigned int)f2bf(hi) << 16);
}

__device__ __forceinline__ void gload_lds16(const void* g, void* l) {
  __builtin_amdgcn_global_load_lds((const __attribute__((address_space(1))) void*)g,
                                   (__attribute__((address_space(3))) void*)l,
                                   16, 0, 0);
}

// ---------------- W conversion (k=0 trimmed, feature-major, i-pair) + bias ----------------
__global__ __launch_bounds__(256) void wconv_kernel(const float* __restrict__ a,
                                                    const float* __restrict__ b,
                                                    unsigned short* __restrict__ W,
                                                    float* __restrict__ bias) {
  int idx = blockIdx.x * 256 + threadIdx.x;
  int o  = idx >> 9;
  int i0 = (idx & 511) * 2;
  const float4* ap = reinterpret_cast<const float4*>(a + (size_t)o * 8192 + i0 * 8);
  const float4* bp = reinterpret_cast<const float4*>(b + (size_t)o * 8192 + i0 * 8);
  float4 a0 = ap[0], a1 = ap[1], a2 = ap[2], a3 = ap[3];
  float4 b0 = bp[0], b1 = bp[1], b2 = bp[2], b3 = bp[3];

  unsigned int* wp = reinterpret_cast<unsigned int*>(W + (size_t)o * KD + i0);
  wp[ 0 * IN_F / 2] = pack2(a0.y, a2.y);
  wp[ 1 * IN_F / 2] = pack2(a0.z, a2.z);
  wp[ 2 * IN_F / 2] = pack2(a0.w, a2.w);
  wp[ 3 * IN_F / 2] = pack2(a1.x, a3.x);
  wp[ 4 * IN_F / 2] = pack2(a1.y, a3.y);
  wp[ 5 * IN_F / 2] = pack2(a1.z, a3.z);
  wp[ 6 * IN_F / 2] = pack2(a1.w, a3.w);
  wp[ 7 * IN_F / 2] = pack2(b0.y, b2.y);
  wp[ 8 * IN_F / 2] = pack2(b0.z, b2.z);
  wp[ 9 * IN_F / 2] = pack2(b0.w, b2.w);
  wp[10 * IN_F / 2] = pack2(b1.x, b3.x);
  wp[11 * IN_F / 2] = pack2(b1.y, b3.y);
  wp[12 * IN_F / 2] = pack2(b1.z, b3.z);
  wp[13 * IN_F / 2] = pack2(b1.w, b3.w);

  float bsum = b0.x + b2.x;
#pragma unroll
  for (int off = 32; off > 0; off >>= 1) bsum += __shfl_down(bsum, off);
  __shared__ float red[4];
  if ((threadIdx.x & 63) == 0) red[threadIdx.x >> 6] = bsum;
  __syncthreads();
  if (threadIdx.x == 0) atomicAdd(&bias[o], red[0] + red[1] + red[2] + red[3]);
}

// ---------------- feature kernel (feature-major, i-pair): Xf[b][j*1024+i] ----------------
__global__ __launch_bounds__(256) void feat_kernel(const float* __restrict__ x,
                                                   unsigned short* __restrict__ Xf) {
  int idx = blockIdx.x * 256 + threadIdx.x;
  int bb = idx >> 9;
  int i0 = (idx & 511) * 2;
  float2 xv = *reinterpret_cast<const float2*>(x + (size_t)bb * IN_F + i0);
  float s1a, c1a, s1b, c1b;
  sincosf(xv.x, &s1a, &c1a);
  sincosf(xv.y, &s1b, &c1b);
  float sa[KF], ca[KF], sb_[KF], cb[KF];
  sa[1] = s1a; ca[1] = c1a; sb_[1] = s1b; cb[1] = c1b;
#pragma unroll
  for (int k = 2; k < KF; ++k) {
    sa[k]  = sa[k-1]*c1a + ca[k-1]*s1a;
    ca[k]  = ca[k-1]*c1a - sa[k-1]*s1a;
    sb_[k] = sb_[k-1]*c1b + cb[k-1]*s1b;
    cb[k]  = cb[k-1]*c1b - sb_[k-1]*s1b;
  }
  unsigned int* dst = reinterpret_cast<unsigned int*>(Xf + (size_t)bb * KD + i0);
#pragma unroll
  for (int j = 0; j < 7; ++j) dst[j * IN_F / 2]       = pack2(sa[j + 1], sb_[j + 1]);
#pragma unroll
  for (int j = 0; j < 7; ++j) dst[(7 + j) * IN_F / 2] = pack2(ca[j + 1], cb[j + 1]);
}

// ---------------- GEMM: 256x256, 8 waves (2x4), intra-tile pipelined, tile-end barrier ----
// Per-tile per wave: burst-stage 8 gload_lds for t+1 (full-tile lead, R3-proven), then
// p0: read {bf x8, af(p0) x4, af(p1) x4}; p>=1: issue af(p+1) then MFMA(p), pinned with
// sched_barrier(0) so the compiler emits COUNTED lgkmcnt(4) before each MFMA cluster
// (no intra-tile barriers -> the 2 waves/SIMD drift; one wave's MFMA covers the other's
// LDS-port window). Floor = max(port ~3074, MFMA 2483) cy/tile vs R5-R7's serial ~4930.
// vmcnt(0)+s_barrier only at tile end (stage had ~2400 cy lead -> drain ~free).
// T2 XOR swizzle via pre-swizzled global source + swizzled ds_read (0 conflicts R2-R7).
__global__ __launch_bounds__(512, 2) void gemm_kernel(const unsigned short* __restrict__ A,
                                                      const unsigned short* __restrict__ Bt,
                                                      float* __restrict__ Cout,
                                                      int use_slab) {
  __shared__ unsigned short sA[2][BM * BK];   // 32 KiB each
  __shared__ unsigned short sB[2][BN * BK];

  const int tid  = threadIdx.x;
  const int wid  = tid >> 6;
  const int lane = tid & 63;
  const int wm = wid >> 2, wn = wid & 3;

  // bijective XCD swizzle: 256 blocks % 8 XCDs == 0
  const int bid = blockIdx.x;
  const int s   = (bid & 7) * 32 + (bid >> 3);
  const int z   = s >> 6;
  const int mt  = s & 15;
  const int nt  = (s >> 4) & 3;
  const int m0  = mt * BM;
  const int n0  = nt * BN;
  const int fbase = z * KCHUNK;

  // ---- staging addressing (pre-swizzled global source, linear LDS dest) ----
  const int srow = wid * 8 + (lane >> 3);
  const int gsw  = (lane & 7) ^ (lane >> 3);
  const unsigned short* pA = A  + (size_t)(m0 + srow) * KD + fbase + gsw * 8;
  const unsigned short* pB = Bt + (size_t)(n0 + srow) * KD + fbase + gsw * 8;
  const int ldst = wid * 512;

  // ---- fragment read addressing (swizzled) ----
  const int l15 = lane & 15;
  int kfrag[2];
#pragma unroll
  for (int ks = 0; ks < 2; ++ks)
    kfrag[ks] = ((ks * 64 + (lane >> 4) * 16) ^ ((lane & 7) << 4)) >> 1;
  const int arow = wm * 128 + l15;
  const int brow = wn * 64 + l15;

  f32x4 acc[8][4] = {};
  short8 bfr[4][2];

#define AFREAD(DST, P)                                                          \
  _Pragma("unroll") for (int i = 0; i < 2; ++i)                                 \
    _Pragma("unroll") for (int ks = 0; ks < 2; ++ks)                            \
      DST[i][ks] = *reinterpret_cast<const short8*>(                            \
          sAc + (arow + (2 * (P) + i) * 16) * 64 + kfrag[ks]);

#define MFMAC(SRC, P)                                                           \
  __builtin_amdgcn_s_setprio(1);                                                \
  _Pragma("unroll") for (int i = 0; i < 2; ++i)                                 \
    _Pragma("unroll") for (int nf = 0; nf < 4; ++nf)                            \
      _Pragma("unroll") for (int ks = 0; ks < 2; ++ks)                          \
        acc[2 * (P) + i][nf] = __builtin_amdgcn_mfma_f32_16x16x32_bf16(         \
            SRC[i][ks], bfr[nf][ks], acc[2 * (P) + i][nf], 0, 0, 0);            \
  __builtin_amdgcn_s_setprio(0);

  // ---- prologue: stage tile 0 -> buf 0 ----
#pragma unroll
  for (int g = 0; g < 4; ++g) {
    gload_lds16(pB + (size_t)g * 64 * KD, &sB[0][g * 4096 + ldst]);
    gload_lds16(pA + (size_t)g * 64 * KD, &sA[0][g * 4096 + ldst]);
  }
  asm volatile("s_waitcnt vmcnt(0)\n\ts_barrier" ::: "memory");

  for (int t = 0; t < NT; ++t) {
    const int c  = t & 1;
    const int cn = c ^ 1;
    const int ktn = (t + 1 < NT) ? (t + 1) * BK : 0;   // dead-wrap keeps ledger uniform
    const unsigned short* sAc = &sA[c][0];
    const unsigned short* sBc = &sB[c][0];

    // burst-stage next tile into the other buffer (WAR safe: prev barrier published)
#pragma unroll
    for (int g = 0; g < 4; ++g) {
      gload_lds16(pB + (size_t)g * 64 * KD + ktn, &sB[cn][g * 4096 + ldst]);
      gload_lds16(pA + (size_t)g * 64 * KD + ktn, &sA[cn][g * 4096 + ldst]);
    }

    short8 afA[2][2], afB[2][2];
    // p0 reads: bf first, then af(p0), then af(p1) last (so pre-MFMA wait is counted)
#pragma unroll
    for (int nf = 0; nf < 4; ++nf)
#pragma unroll
      for (int ks = 0; ks < 2; ++ks)
        bfr[nf][ks] = *reinterpret_cast<const short8*>(
            sBc + (brow + nf * 16) * 64 + kfrag[ks]);
    AFREAD(afA, 0)
    AFREAD(afB, 1)
    __builtin_amdgcn_sched_barrier(0);
    MFMAC(afA, 0)                          // compiler waits lgkmcnt(4): af(p1) in flight
    __builtin_amdgcn_sched_barrier(0);
    AFREAD(afA, 2)                         // issue p2 reads
    __builtin_amdgcn_sched_barrier(0);
    MFMAC(afB, 1)                          // lgkmcnt(4): af(p2) in flight
    __builtin_amdgcn_sched_barrier(0);
    AFREAD(afB, 3)                         // issue p3 reads
    __builtin_amdgcn_sched_barrier(0);
    MFMAC(afA, 2)                          // lgkmcnt(4): af(p3) in flight
    __builtin_amdgcn_sched_barrier(0);
    MFMAC(afB, 3)                          // lgkmcnt(0)
    __builtin_amdgcn_sched_barrier(0);

    // publish staged buffer (stage loads had a full tile to land)
    asm volatile("s_waitcnt vmcnt(0)\n\ts_barrier" ::: "memory");
  }
#undef AFREAD
#undef MFMAC

  // ---- epilogue ----
  const int crow = m0 + wm * 128 + (lane >> 4) * 4;
  const int ccol = n0 + wn * 64 + l15;
  if (use_slab) {
    float* Cz = Cout + (size_t)z * C_ELEMS;
#pragma unroll
    for (int mf = 0; mf < 8; ++mf)
#pragma unroll
      for (int nf = 0; nf < 4; ++nf)
#pragma unroll
        for (int j = 0; j < 4; ++j)
          Cz[(size_t)(crow + mf * 16 + j) * OUT_F + ccol + nf * 16] = acc[mf][nf][j];
  } else {
#pragma unroll
    for (int mf = 0; mf < 8; ++mf)
#pragma unroll
      for (int nf = 0; nf < 4; ++nf)
#pragma unroll
        for (int j = 0; j < 4; ++j)
          atomicAdd(&Cout[(size_t)(crow + mf * 16 + j) * OUT_F + ccol + nf * 16],
                    acc[mf][nf][j]);
  }
}

// ---------------- K-split slab reduce + bias ----------------
__global__ __launch_bounds__(256) void reduce_kernel(const f32x4* __restrict__ s,
                                                     const float* __restrict__ bias,
                                                     f32x4* __restrict__ y) {
  size_t i = (size_t)blockIdx.x * 256 + threadIdx.x;
  const size_t NQ = C_ELEMS / 4;
  f32x4 v = s[i] + s[i + NQ] + s[i + 2 * NQ] + s[i + 3 * NQ];
  v += reinterpret_cast<const f32x4*>(bias)[i & 255];
  y[i] = v;
}

// ---------------- bias broadcast (atomic-fallback init) ----------------
__global__ __launch_bounds__(256) void binit_kernel(const float* __restrict__ bias,
                                                    f32x4* __restrict__ y) {
  size_t i = (size_t)blockIdx.x * 256 + threadIdx.x;
  y[i] = reinterpret_cast<const f32x4*>(bias)[i & 255];
}

// ---------------- fallback (no workspace): direct f32 evaluation ----------------
__global__ __launch_bounds__(256) void naive_kernel(const float* __restrict__ x,
                                                    const float* __restrict__ a,
                                                    const float* __restrict__ b,
                                                    float* __restrict__ y) {
  int o  = blockIdx.x * 256 + threadIdx.x;
  int bb = blockIdx.y;
  __shared__ float xs[IN_F];
  for (int i = threadIdx.x; i < IN_F; i += 256) xs[i] = x[(size_t)bb * IN_F + i];
  __syncthreads();
  float acc = 0.f;
  for (int i = 0; i < IN_F; ++i) {
    float s1, c1; sincosf(xs[i], &s1, &c1);
    float sk = 0.f, ck = 1.f;
    const float* ap = a + (size_t)o * 8192 + i * KF;
    const float* bp = b + (size_t)o * 8192 + i * KF;
#pragma unroll
    for (int k = 0; k < KF; ++k) {
      acc += sk * ap[k] + ck * bp[k];
      float sn = sk * c1 + ck * s1;
      ck = ck * c1 - sk * s1;
      sk = sn;
    }
  }
  y[(size_t)bb * OUT_F + o] = acc;
}

extern "C" void kernel_launch(void* const* d_in, const int* in_sizes, int n_in,
                              void* d_out, int out_size, void* d_ws, size_t ws_size,
                              hipStream_t stream) {
  (void)in_sizes; (void)n_in; (void)out_size;
  const float* x = (const float*)d_in[0];
  const float* a = (const float*)d_in[1];
  const float* b = (const float*)d_in[2];
  float* y = (float*)d_out;

  const size_t XF_BYTES   = (size_t)BATCH * KD * sizeof(unsigned short);   // 112 MiB
  const size_t W_BYTES    = (size_t)OUT_F * KD * sizeof(unsigned short);   // 28 MiB
  const size_t BIAS_BYTES = (size_t)OUT_F * sizeof(float);                 // 4 KiB
  const size_t SLAB_BYTES = C_ELEMS * sizeof(float) * KSPLIT;              // 64 MiB

  if (ws_size >= XF_BYTES + W_BYTES + BIAS_BYTES) {
    unsigned short* Xf = (unsigned short*)d_ws;
    unsigned short* W  = (unsigned short*)((char*)d_ws + XF_BYTES);
    float* bias        = (float*)((char*)d_ws + XF_BYTES + W_BYTES);
    float* slabs       = (float*)((char*)d_ws + XF_BYTES + W_BYTES + BIAS_BYTES);
    const bool slab = ws_size >= XF_BYTES + W_BYTES + BIAS_BYTES + SLAB_BYTES;

    hipMemsetAsync(bias, 0, BIAS_BYTES, stream);
    wconv_kernel<<<(OUT_F * IN_F / 2) / 256, 256, 0, stream>>>(a, b, W, bias);
    feat_kernel<<<(BATCH * IN_F / 2) / 256, 256, 0, stream>>>(x, Xf);
    if (slab) {
      gemm_kernel<<<dim3((BATCH / BM) * (OUT_F / BN) * KSPLIT), 512, 0, stream>>>(Xf, W, slabs, 1);
      reduce_kernel<<<(int)(C_ELEMS / 4 / 256), 256, 0, stream>>>((const f32x4*)slabs, bias, (f32x4*)y);
    } else {
      binit_kernel<<<(int)(C_ELEMS / 4 / 256), 256, 0, stream>>>(bias, (f32x4*)y);
      gemm_kernel<<<dim3((BATCH / BM) * (OUT_F / BN) * KSPLIT), 512, 0, stream>>>(Xf, W, y, 0);
    }
  } else {
    naive_kernel<<<dim3(OUT_F / 256, BATCH), 256, 0, stream>>>(x, a, b, y);
  }
}